// Round 8
// baseline (506.329 us; speedup 1.0000x reference)
//
#include <hip/hip_runtime.h>
#include <cstddef>

// Bit-exact OpenBLAS-skylakex (KC=320) fp32 SNN — two-kernel split.
// The three K-panels [0,320),[320,640),[640,784) are INDEPENDENT fmaf chains;
// K1 computes each panel in its own block (1536 blocks = 3x parallelism of the
// fused GEMM), K2 folds ((P1+P2)+P3)+b1 (exact, elementwise) and runs the 20
// LIF steps at high occupancy (2048 blocks), streaming the 330 MB spk1_rec.
// Chain order identical to r4 (PASSED): k ascending, ascending-j layer2 with
// fmaf(2^b*bit, W2*2^-b, mm) products exact; cur2=mm+b2 then m2*0.25+cur2.

constexpr int BROWS  = 64;
constexpr int BK     = 16;
constexpr int NJ     = 128;
constexpr int KDIM   = 784;
constexpr int NO     = 10;
constexpr int TSTEPS = 20;
constexpr int BR2    = 16;    // rows per block in K2

// ---------------- K1: one KC=320 panel per block ----------------
__global__ __launch_bounds__(256, 4) void gemm_panel(
    const float* __restrict__ x,
    const float* __restrict__ W1,
    float* __restrict__ pout,
    int B)
{
    __shared__ alignas(16) float xs[BK][68];     // [kk][row+pad]
    __shared__ alignas(16) float ws[BK][192];    // [kk][16 chunks * 12]

    const int t  = threadIdx.x;
    const int tx = t & 15;                        // cols j = tx*8+jj
    const int ty = t >> 4;                        // rows r = ty*4+rr
    const int r0 = blockIdx.x * BROWS;
    const int p  = blockIdx.y;                    // panel 0/1/2
    const int kbase = p * 320;
    const int NT = (p < 2) ? 20 : 9;              // 320/320/144 k

    float acc[4][8];
    #pragma unroll
    for (int rr = 0; rr < 4; ++rr)
        #pragma unroll
        for (int jj = 0; jj < 8; ++jj) acc[rr][jj] = 0.0f;

    const int xrow = t >> 2, xkf = (t & 3) * 4;
    const int wj   = t >> 1, wkf = (t & 1) * 8;
    const int wco  = wj >> 3, wci = wj & 7;
    const float* xrp = x  + (size_t)(r0 + xrow) * KDIM + kbase + xkf;
    const float* wrp = W1 + (size_t)wj * KDIM + kbase + wkf;

    #pragma unroll 1
    for (int tt = 0; tt < NT; ++tt) {
        const int k0 = tt * BK;
        float4 xv = *(const float4*)(xrp + k0);
        float4 wa = *(const float4*)(wrp + k0);
        float4 wb = *(const float4*)(wrp + k0 + 4);
        xs[xkf + 0][xrow] = xv.x; xs[xkf + 1][xrow] = xv.y;
        xs[xkf + 2][xrow] = xv.z; xs[xkf + 3][xrow] = xv.w;
        float* wp0 = &ws[wkf][wco * 12 + wci];    // stride 192 rows
        wp0[0]    = wa.x; wp0[192]  = wa.y; wp0[384]  = wa.z; wp0[576]  = wa.w;
        wp0[768]  = wb.x; wp0[960]  = wb.y; wp0[1152] = wb.z; wp0[1344] = wb.w;
        __syncthreads();
        #pragma unroll
        for (int kk = 0; kk < BK; ++kk) {         // strict ascending k
            float4 xr  = *(const float4*)&xs[kk][ty * 4];
            float4 wva = *(const float4*)&ws[kk][tx * 12];
            float4 wvb = *(const float4*)&ws[kk][tx * 12 + 4];
            float xf[4] = {xr.x, xr.y, xr.z, xr.w};
            float wf[8] = {wva.x, wva.y, wva.z, wva.w, wvb.x, wvb.y, wvb.z, wvb.w};
            #pragma unroll
            for (int rr = 0; rr < 4; ++rr)
                #pragma unroll
                for (int jj = 0; jj < 8; ++jj)
                    acc[rr][jj] = fmaf(xf[rr], wf[jj], acc[rr][jj]);
        }
        __syncthreads();
    }

    float* dst = pout + (size_t)p * B * NJ;
    #pragma unroll
    for (int rr = 0; rr < 4; ++rr) {
        size_t base = (size_t)(r0 + ty * 4 + rr) * NJ + tx * 8;
        float4 fa; fa.x = acc[rr][0]; fa.y = acc[rr][1]; fa.z = acc[rr][2]; fa.w = acc[rr][3];
        float4 fb; fb.x = acc[rr][4]; fb.y = acc[rr][5]; fb.z = acc[rr][6]; fb.w = acc[rr][7];
        *(float4*)&dst[base]     = fa;
        *(float4*)&dst[base + 4] = fb;
    }
}

// ---------------- K2: fold panels + 20 LIF steps ----------------
__global__ __launch_bounds__(256, 4) void snn_dyn(
    const float* __restrict__ pout,
    const float* __restrict__ b1,
    const float* __restrict__ W2,
    const float* __restrict__ b2,
    float* __restrict__ out,
    int B)
{
    __shared__ float w2v[NJ][12];                 // [j][o]: W2[o][j]*2^-(j&31)
    __shared__ unsigned smask[2][BR2][20];        // stride 20: 16B-aligned rows

    const int t  = threadIdx.x;
    const int tx = t & 15;                        // j oct: j = tx*8+jj
    const int ty = t >> 4;                        // row 0..15
    const int r0 = blockIdx.x * BR2;

    for (int e = t; e < NJ * NO; e += 256) {
        int o = e >> 7, j = e & 127;
        float sc = __int_as_float((127 - (j & 31)) << 23);   // 2^-(j&31), exact
        w2v[j][o] = W2[o * NJ + j] * sc;
    }

    // fold cur = ((P1+P2)+P3)+b1  (exact, elementwise)
    const size_t ps = (size_t)B * NJ;
    const float* prow = pout + (size_t)(r0 + ty) * NJ + tx * 8;
    float4 p1a = *(const float4*)(prow);
    float4 p1b = *(const float4*)(prow + 4);
    float4 p2a = *(const float4*)(prow + ps);
    float4 p2b = *(const float4*)(prow + ps + 4);
    float4 p3a = *(const float4*)(prow + 2 * ps);
    float4 p3b = *(const float4*)(prow + 2 * ps + 4);
    float4 ba  = *(const float4*)(b1 + tx * 8);
    float4 bb  = *(const float4*)(b1 + tx * 8 + 4);
    float cur[8], mem1[8];
    {
        float p1[8] = {p1a.x, p1a.y, p1a.z, p1a.w, p1b.x, p1b.y, p1b.z, p1b.w};
        float p2[8] = {p2a.x, p2a.y, p2a.z, p2a.w, p2b.x, p2b.y, p2b.z, p2b.w};
        float p3[8] = {p3a.x, p3a.y, p3a.z, p3a.w, p3b.x, p3b.y, p3b.z, p3b.w};
        float bf[8] = {ba.x, ba.y, ba.z, ba.w, bb.x, bb.y, bb.z, bb.w};
        #pragma unroll
        for (int jj = 0; jj < 8; ++jj) {
            cur[jj]  = ((p1[jj] + p2[jj]) + p3[jj]) + bf[jj];
            mem1[jj] = 0.0f;
        }
    }

    const bool cons = (t < 160);                  // consumer: (row, o)
    const int  crow = t / 10;
    const int  co   = t - crow * 10;
    float m2 = 0.0f, cnt = 0.0f;
    float b2o = cons ? b2[co] : 0.0f;
    float* rec = out + (size_t)B * NO;

    __syncthreads();                              // w2v ready

    #pragma unroll 1
    for (int st = 0; st < TSTEPS; ++st) {
        const int p = st & 1;
        unsigned bt = 0;
        float s0[8];
        #pragma unroll
        for (int jj = 0; jj < 8; ++jj) {
            float m = fmaf(mem1[jj], 0.25f, cur[jj]);   // *0.25 exact
            bool  s = (m - 1.0f) > 0.0f;
            s0[jj] = s ? 1.0f : 0.0f;
            mem1[jj] = s ? 0.0f : m;
            bt |= s ? (1u << jj) : 0u;
        }
        size_t base = ((size_t)st * B + (size_t)(r0 + ty)) * NJ + tx * 8;
        float4 fa; fa.x = s0[0]; fa.y = s0[1]; fa.z = s0[2]; fa.w = s0[3];
        float4 fb; fb.x = s0[4]; fb.y = s0[5]; fb.z = s0[6]; fb.w = s0[7];
        *(float4*)&rec[base]     = fa;
        *(float4*)&rec[base + 4] = fb;
        ((unsigned char*)&smask[p][ty][0])[tx] = (unsigned char)bt;
        __syncthreads();
        if (cons) {
            uint4 mr = *(const uint4*)&smask[p][crow][0];
            unsigned mw[4] = {mr.x, mr.y, mr.z, mr.w};
            float mm = 0.0f;
            #pragma unroll
            for (int w = 0; w < 4; ++w) {
                unsigned bits = mw[w];
                #pragma unroll
                for (int b = 0; b < 32; ++b) {    // strict ascending j
                    float f = (float)(bits & (1u << b));     // 0 or 2^b, exact
                    mm = fmaf(f, w2v[w * 32 + b][co], mm);   // = mm + W2 exactly
                }
            }
            float cur2 = mm + b2o;                // np: chain + b2
            float nm   = fmaf(m2, 0.25f, cur2);   // then decay add (exact mul)
            bool  s2   = (nm - 1.0f) > 0.0f;
            cnt += s2 ? 1.0f : 0.0f;
            m2  = s2 ? 0.0f : nm;
        }
    }

    if (cons) out[(size_t)(r0 + crow) * NO + co] = cnt;
}

// ---------------- fallback: r4 fused kernel (ws too small) ----------------
__global__ __launch_bounds__(256, 2) void snn_fused_fb(
    const float* __restrict__ x,
    const float* __restrict__ W1,
    const float* __restrict__ b1,
    const float* __restrict__ W2,
    const float* __restrict__ b2,
    float* __restrict__ out,
    int B)
{
    __shared__ alignas(16) float xs[BK][68];
    __shared__ alignas(16) float ws[BK][192];
    __shared__ alignas(16) float4 w2s[NJ][3];
    __shared__ unsigned smaskW[2][BROWS][17];
    __shared__ float b2s[12];

    const int t  = threadIdx.x;
    const int tx = t & 15;
    const int ty = t >> 4;
    const int r0 = blockIdx.x * BROWS;

    for (int e = t; e < NJ * 3; e += 256) {
        int og = e % 3, j = e / 3;
        float sc = __int_as_float((127 - (j & 31)) << 23);
        float vv[4];
        #pragma unroll
        for (int c = 0; c < 4; ++c) {
            int o = og * 4 + c;
            vv[c] = (o < NO) ? W2[o * NJ + j] * sc : 0.0f;
        }
        float4 v; v.x = vv[0]; v.y = vv[1]; v.z = vv[2]; v.w = vv[3];
        w2s[j][og] = v;
    }
    if (t < 12) b2s[t] = (t < NO) ? b2[t] : 0.0f;

    float acc[4][8], cur[4][8];
    #pragma unroll
    for (int rr = 0; rr < 4; ++rr)
        #pragma unroll
        for (int jj = 0; jj < 8; ++jj) { acc[rr][jj] = 0.0f; cur[rr][jj] = 0.0f; }

    const int xrow = t >> 2, xkf = (t & 3) * 4;
    const int wj   = t >> 1, wkf = (t & 1) * 8;
    const int wco  = wj >> 3, wci = wj & 7;
    const float* xrp = x  + (size_t)(r0 + xrow) * KDIM + xkf;
    const float* wrp = W1 + (size_t)wj * KDIM + wkf;

    #pragma unroll 1
    for (int tt = 0; tt < 49; ++tt) {
        const int k0 = tt * BK;
        float4 xv = *(const float4*)(xrp + k0);
        float4 wa = *(const float4*)(wrp + k0);
        float4 wb = *(const float4*)(wrp + k0 + 4);
        xs[xkf + 0][xrow] = xv.x; xs[xkf + 1][xrow] = xv.y;
        xs[xkf + 2][xrow] = xv.z; xs[xkf + 3][xrow] = xv.w;
        float* wp0 = &ws[wkf][wco * 12 + wci];
        wp0[0]    = wa.x; wp0[192]  = wa.y; wp0[384]  = wa.z; wp0[576]  = wa.w;
        wp0[768]  = wb.x; wp0[960]  = wb.y; wp0[1152] = wb.z; wp0[1344] = wb.w;
        __syncthreads();
        #pragma unroll
        for (int kk = 0; kk < BK; ++kk) {
            float4 xr  = *(const float4*)&xs[kk][ty * 4];
            float4 wva = *(const float4*)&ws[kk][tx * 12];
            float4 wvb = *(const float4*)&ws[kk][tx * 12 + 4];
            float xf[4] = {xr.x, xr.y, xr.z, xr.w};
            float wf[8] = {wva.x, wva.y, wva.z, wva.w, wvb.x, wvb.y, wvb.z, wvb.w};
            #pragma unroll
            for (int rr = 0; rr < 4; ++rr)
                #pragma unroll
                for (int jj = 0; jj < 8; ++jj)
                    acc[rr][jj] = fmaf(xf[rr], wf[jj], acc[rr][jj]);
        }
        __syncthreads();
        if (tt == 19) {
            #pragma unroll
            for (int rr = 0; rr < 4; ++rr)
                #pragma unroll
                for (int jj = 0; jj < 8; ++jj) { cur[rr][jj] = acc[rr][jj]; acc[rr][jj] = 0.0f; }
        } else if (tt == 39) {
            #pragma unroll
            for (int rr = 0; rr < 4; ++rr)
                #pragma unroll
                for (int jj = 0; jj < 8; ++jj) { cur[rr][jj] = cur[rr][jj] + acc[rr][jj]; acc[rr][jj] = 0.0f; }
        }
    }
    {
        const float* b1p = b1 + tx * 8;
        float4 ba = *(const float4*)b1p, bb = *(const float4*)(b1p + 4);
        float bf[8] = {ba.x, ba.y, ba.z, ba.w, bb.x, bb.y, bb.z, bb.w};
        #pragma unroll
        for (int rr = 0; rr < 4; ++rr)
            #pragma unroll
            for (int jj = 0; jj < 8; ++jj)
                cur[rr][jj] = (cur[rr][jj] + acc[rr][jj]) + bf[jj];
    }

    float mem1[4][8];
    #pragma unroll
    for (int rr = 0; rr < 4; ++rr)
        #pragma unroll
        for (int jj = 0; jj < 8; ++jj) mem1[rr][jj] = 0.0f;

    const int row_l2 = t & 63;
    const int og     = t >> 6;
    float m2[4]  = {0.f, 0.f, 0.f, 0.f};
    float cnt[4] = {0.f, 0.f, 0.f, 0.f};
    float* rec = out + (size_t)B * NO;

    #pragma unroll 1
    for (int st = 0; st < TSTEPS; ++st) {
        const int p = st & 1;
        #pragma unroll
        for (int rr = 0; rr < 4; ++rr) {
            unsigned bt = 0;
            float s0[8];
            #pragma unroll
            for (int jj = 0; jj < 8; ++jj) {
                float m = fmaf(mem1[rr][jj], 0.25f, cur[rr][jj]);
                float v = m - 1.0f;
                bool  s = v > 0.0f;
                s0[jj] = s ? 1.0f : 0.0f;
                mem1[rr][jj] = s ? 0.0f : m;
                bt |= s ? (1u << jj) : 0u;
            }
            size_t base = ((size_t)st * B + (size_t)(r0 + ty * 4 + rr)) * NJ + tx * 8;
            float4 fa; fa.x = s0[0]; fa.y = s0[1]; fa.z = s0[2]; fa.w = s0[3];
            float4 fb; fb.x = s0[4]; fb.y = s0[5]; fb.z = s0[6]; fb.w = s0[7];
            *(float4*)&rec[base]     = fa;
            *(float4*)&rec[base + 4] = fb;
            ((unsigned char*)&smaskW[p][ty * 4 + rr][0])[tx] = (unsigned char)bt;
        }
        __syncthreads();
        if (og < 3) {
            unsigned mw[4];
            #pragma unroll
            for (int w = 0; w < 4; ++w) mw[w] = smaskW[p][row_l2][w];
            float mm[4] = {0.f, 0.f, 0.f, 0.f};
            #pragma unroll
            for (int w = 0; w < 4; ++w) {
                unsigned bits = mw[w];
                #pragma unroll
                for (int b = 0; b < 32; ++b) {
                    float f = (float)(bits & (1u << b));
                    float4 wv = w2s[w * 32 + b][og];
                    mm[0] = fmaf(f, wv.x, mm[0]);
                    mm[1] = fmaf(f, wv.y, mm[1]);
                    mm[2] = fmaf(f, wv.z, mm[2]);
                    mm[3] = fmaf(f, wv.w, mm[3]);
                }
            }
            #pragma unroll
            for (int c = 0; c < 4; ++c) {
                float cur2 = mm[c] + b2s[og * 4 + c];
                float nm   = fmaf(m2[c], 0.25f, cur2);
                float v2   = nm - 1.0f;
                bool  s2   = v2 > 0.0f;
                cnt[c] += s2 ? 1.0f : 0.0f;
                m2[c]  = s2 ? 0.0f : nm;
            }
        }
    }

    if (og < 3) {
        #pragma unroll
        for (int c = 0; c < 4; ++c) {
            int o = og * 4 + c;
            if (o < NO) out[(size_t)(r0 + row_l2) * NO + o] = cnt[c];
        }
    }
}

extern "C" void kernel_launch(void* const* d_in, const int* in_sizes, int n_in,
                              void* d_out, int out_size, void* d_ws, size_t ws_size,
                              hipStream_t stream)
{
    const float* x  = (const float*)d_in[0];
    const float* W1 = (const float*)d_in[1];
    const float* b1 = (const float*)d_in[2];
    const float* W2 = (const float*)d_in[3];
    const float* b2 = (const float*)d_in[4];
    float* out = (float*)d_out;
    const int B = in_sizes[0] / KDIM;       // 32768

    const size_t need = (size_t)3 * B * NJ * sizeof(float);   // 50.3 MB
    if (ws_size >= need) {
        dim3 g1(B / BROWS, 3);
        gemm_panel<<<g1, 256, 0, stream>>>(x, W1, (float*)d_ws, B);
        snn_dyn<<<B / BR2, 256, 0, stream>>>((const float*)d_ws, b1, W2, b2, out, B);
    } else {
        snn_fused_fb<<<B / BROWS, 256, 0, stream>>>(x, W1, b1, W2, b2, out, B);
    }
}